// Round 5
// baseline (368.132 us; speedup 1.0000x reference)
//
#include <hip/hip_runtime.h>

// (B,C,D,H,W) = (2,64,32,64,64), R=2, NCH=125
#define B_ 2
#define C_ 64
#define D_ 32
#define H_ 64
#define W_ 64
#define NCH 125
#define HW_ 4096
#define DHW_ 131072
#define CDHW_ 8388608

// R5 design: NO LDS. x2 is L2/L3-resident (R3: FETCH 95MB vs ~600MB logical
// reads), so LDS staging bought only ~3x reuse while (a) serializing every
// iteration on a global_load_lds round-trip at the vmcnt gate and (b) pushing
// 12 conflicted ds_read_b64 per wave-iter through the shared DS pipe (~60%
// busy, 1.57e7 conflict cycles). Instead each lane loads its own patch
// directly (L1/L2 hit), software-pipelined distance-1 in registers:
//   per row k in [y-2, y+2]: float2 @ cols x+2..x+3, float2 @ x+4..x+5
//   row y-2 extra:           float2 @ x-2..x-1,      float2 @ x..x+1
// All loads 8B-aligned, 32-bit dword offsets off a uniform SGPR base.
// Out-of-range rows / halo cols: offsets CLAMPED in-bounds, values masked to
// zero in compute (== reference zero-padding). No OOB access anywhere.
// R4 lesson: keep the 16 dead-channel zero stores SPREAD in-loop (epilogue
// batching un-overlaps the 131MB write stream: +27us).
// R3 lesson: nt stores keep the write stream out of L2/L3 (FETCH 300->95MB).

typedef float f32x4 __attribute__((ext_vector_type(4)));

__device__ __forceinline__ void nt_store4(float* p, float a, float b,
                                          float c, float d) {
    f32x4 v = {a, b, c, d};
    __builtin_nontemporal_store(v, (f32x4*)p);
}

// Live offsets form an L: s=i+j in [-4..4], last-write winner is
//   s<=0 -> (i,j)=(s+2,-2): rows y-2..y+2, cols x+2..x+5  (acc[4-k])
//   s>=0 -> (i,j)=(2,s-2) : row y-2, cols x+2-s           (acc[s+4])
// ch=(5s+h) mod 125 -> live {0..22}u{103..124}; 23..102 identically zero.
__global__ __launch_bounds__(128, 4) void cv_all(const float* __restrict__ x1,
                                                 const float* __restrict__ x2,
                                                 float* __restrict__ out)
{
    const int tid  = threadIdx.y * 16 + threadIdx.x;
    const int lane = tid & 63;
    const int w    = tid >> 6;             // wave 0/1
    const int tx   = lane & 15;            // x quad
    const int lr0  = lane >> 4;            // 0..3: row within wave

    // XCD-grouped swizzle: XCD m owns d-slice [4m,4m+4) -> hh re-reads L2-hit
    const int lin     = blockIdx.x;                    // 0..2559
    const int logical = (lin & 7) * 320 + (lin >> 3);
    const int bz   = logical % 10;
    const int rest = logical / 10;
    const int y0   = (rest & 7) * 8;
    const int d    = rest >> 3;
    const int b    = bz / 5;
    const int hi   = bz - b * 5;           // 0..4
    const int hh   = hi - 2;               // depth shift in [-2,2]
    const int y    = y0 + 4 * w + lr0;     // output row, 0..63
    const int x    = tx * 4;               // output col quad base
    const int zd   = d - hh;
    const bool zok = (zd >= 0) && (zd < D_);
    const bool lo_edge = (tx == 0);
    const bool hi_edge = (tx == 15);

    const int zdc = zok ? zd : 0;          // clamped depth (masked if !zok)
    const float* xb2 = x2 + (size_t)b * CDHW_;   // uniform SGPR base
    const float* xb1 = x1 + (size_t)b * CDHW_;   // uniform SGPR base

    // Per-lane row masks + clamped in-bounds 32-bit dword offsets.
    bool mRow[5], mB[5];
    int  offA[5], offB[5];
    const int colB = hi_edge ? 60 : (x + 4);     // hi_edge: in-row garbage, masked
#pragma unroll
    for (int k = 0; k < 5; ++k) {
        const int yy  = y - 2 + k;               // [-2, 65]
        mRow[k] = zok && (yy >= 0) && (yy < H_);
        mB[k]   = mRow[k] && !hi_edge;
        const int yyc = yy < 0 ? 0 : (yy > 63 ? 63 : yy);
        offA[k] = zdc * HW_ + yyc * W_ + (x + 2);    // cols x+2,x+3 (always in-row)
        offB[k] = zdc * HW_ + yyc * W_ + colB;       // cols x+4,x+5 (or masked)
    }
    const bool mLB = mRow[0];                    // row y-2, cols x,x+1
    const bool mLA = mRow[0] && !lo_edge;        // row y-2, cols x-2,x-1
    const int yyc0 = (y - 2) < 0 ? 0 : (y - 2);
    int offLA = zdc * HW_ + yyc0 * W_ + (lo_edge ? 0 : (x - 2));
    // rlB (row y-2, cols x,x+1) loads from offA[0] - 2 (same row, 16B-aligned)

    int off1 = d * HW_ + y * W_ + x;             // x1, always valid

    // dead-channel output base (16 zero channels per hi, spread over loop)
    float* obz = out + (size_t)b * NCH * DHW_ + (size_t)(23 + hi * 16) * DHW_
                     + (size_t)d * HW_ + (y * W_ + x);

    // ---- preamble: slab 0 -> cur regs; advance offsets to slab 1
    float2 cA[5], cB[5];
#pragma unroll
    for (int k = 0; k < 5; ++k) {
        cA[k] = *(const float2*)(xb2 + offA[k]);
        cB[k] = *(const float2*)(xb2 + offB[k]);
    }
    float2 cLA = *(const float2*)(xb2 + offLA);
    float2 cLB = *(const float2*)(xb2 + offA[0] - 2);
    float4 a0  = *(const float4*)(xb1 + off1);
#pragma unroll
    for (int k = 0; k < 5; ++k) { offA[k] += DHW_; offB[k] += DHW_; }
    offLA += DHW_; off1 += DHW_;

    float acc[9][4];
#pragma unroll
    for (int k = 0; k < 9; ++k)
#pragma unroll
        for (int j = 0; j < 4; ++j) acc[k][j] = 0.f;

#pragma unroll 2
    for (int c = 0; c < C_; ++c) {
        // 1. issue slab c+1 loads (13 independent vmem, L1/L2-hit)
        float2 nA[5], nB[5];
#pragma unroll
        for (int k = 0; k < 5; ++k) {
            nA[k] = *(const float2*)(xb2 + offA[k]);
            nB[k] = *(const float2*)(xb2 + offB[k]);
        }
        float2 nLA = *(const float2*)(xb2 + offLA);
        float2 nLB = *(const float2*)(xb2 + offA[0] - 2);
        float4 na  = *(const float4*)(xb1 + off1);
        if (c < 62) {                      // c=62 issued slab 63; c=63 re-issues
#pragma unroll                             // slab 63 (discarded, in-bounds)
            for (int k = 0; k < 5; ++k) { offA[k] += DHW_; offB[k] += DHW_; }
            offLA += DHW_; off1 += DHW_;
        }

        // 2. compute slab c from cur regs (mask = zero-padding semantics)
        const float4 a = a0;
        float k0A0, k0A1, k0B0, k0B1;
#pragma unroll
        for (int k = 0; k < 5; ++k) {      // rows y-2..y+2
            const float vA0 = mRow[k] ? cA[k].x : 0.f;
            const float vA1 = mRow[k] ? cA[k].y : 0.f;
            const float vB0 = mB[k]   ? cB[k].x : 0.f;
            const float vB1 = mB[k]   ? cB[k].y : 0.f;
            if (k == 0) { k0A0 = vA0; k0A1 = vA1; k0B0 = vB0; k0B1 = vB1; }
            const int ai = 4 - k;
            acc[ai][0] += a.x * vA0;
            acc[ai][1] += a.y * vA1;
            acc[ai][2] += a.z * vB0;
            acc[ai][3] += a.w * vB1;
        }
        {                                  // row part: row y-2
            const float rl0 = mLA ? cLA.x : 0.f;
            const float rl1 = mLA ? cLA.y : 0.f;
            const float rl2 = mLB ? cLB.x : 0.f;
            const float rl3 = mLB ? cLB.y : 0.f;
            const float r8[8] = {rl0, rl1, rl2, rl3, k0A0, k0A1, k0B0, k0B1};
#pragma unroll
            for (int s = 1; s <= 4; ++s) { // voxel x+v uses r8[4+v-s]
                const int ai = s + 4;
                acc[ai][0] += a.x * r8[4 - s];
                acc[ai][1] += a.y * r8[5 - s];
                acc[ai][2] += a.z * r8[6 - s];
                acc[ai][3] += a.w * r8[7 - s];
            }
        }

        // 3. rotate pipeline registers (renamed away by unroll-2)
#pragma unroll
        for (int k = 0; k < 5; ++k) { cA[k] = nA[k]; cB[k] = nB[k]; }
        cLA = nLA; cLB = nLB; a0 = na;

        // 4. spread the 16 dead-channel zero stores across the loop (nt)
        if ((c & 3) == 0)
            nt_store4(obz + (size_t)(c >> 2) * DHW_, 0.f, 0.f, 0.f, 0.f);
    }

    // ---- epilogue: 9 live channels (nt stores)
    float* ob = out + (size_t)b * NCH * DHW_ + (size_t)d * HW_ + (y * W_ + x);
    const float inv = 1.0f / 125.0f;
#pragma unroll
    for (int k = 0; k < 9; ++k) {
        const int s = k - 4;
        int ch = 5 * s + hh;
        ch = (ch % NCH + NCH) % NCH;
        nt_store4(ob + (size_t)ch * DHW_,
                  acc[k][0] * inv, acc[k][1] * inv,
                  acc[k][2] * inv, acc[k][3] * inv);
    }
}

extern "C" void kernel_launch(void* const* d_in, const int* in_sizes, int n_in,
                              void* d_out, int out_size, void* d_ws, size_t ws_size,
                              hipStream_t stream) {
    const float* x1 = (const float*)d_in[0];
    const float* x2 = (const float*)d_in[1];
    float* out = (float*)d_out;
    cv_all<<<dim3(2560, 1, 1), dim3(16, 8, 1), 0, stream>>>(x1, x2, out);
}